// Round 10
// baseline (6096.205 us; speedup 1.0000x reference)
//
#include <hip/hip_runtime.h>
#include <math.h>

#define CDIM 256
#define NHEAD 8
#define HD 32
#define BSZ 8
#define NTOK 256
#define MROWS (BSZ*NTOK)   // 2048
#define LN_EPS 1e-5f
#define DT_STEP 0.01f

// Dynamic LDS layout for ode_kernel (bytes):
//   [0,      131072) : W1 packed bf16, [kgroup g][col c] uint4 (8 k's each)
//   [131072, 139264) : bufA[8][256] f32   (feval arg)
//   [139264, 147456) : bufB[8][256] f32   (relu(h))
//   [147456, 147584) : pS[4][8]           (LN sum partials  [wave][row])
//   [147584, 147712) : pQ[4][8]           (LN sumsq partials)
//   [147712, 147744) : mb[8]
//   [147744, 147776) : rb[8]
#define ODE_LDS_BYTES 147776

// ---------------------------------------------------------------------------
// LayerNorm statistics across 256 threads (one column each) for R rows.
// (used by oproj kernel)
// ---------------------------------------------------------------------------
template<int R>
__device__ __forceinline__ void ln_stats(const float* val, int tid,
        float (*part_s)[R], float (*part_q)[R], float* mb, float* rb) {
    const int lane = tid & 63;
    const int wid  = tid >> 6;
    #pragma unroll
    for (int r = 0; r < R; ++r) {
        float s = val[r];
        float q = val[r] * val[r];
        #pragma unroll
        for (int off = 32; off > 0; off >>= 1) {
            s += __shfl_down(s, off, 64);
            q += __shfl_down(q, off, 64);
        }
        if (lane == 0) { part_s[wid][r] = s; part_q[wid][r] = q; }
    }
    __syncthreads();
    if (tid < R) {
        float S = part_s[0][tid] + part_s[1][tid] + part_s[2][tid] + part_s[3][tid];
        float Q = part_q[0][tid] + part_q[1][tid] + part_q[2][tid] + part_q[3][tid];
        float mean = S * (1.0f / CDIM);
        float var  = Q * (1.0f / CDIM) - mean * mean;
        mb[tid] = mean;
        rb[tid] = rsqrtf(var + LN_EPS);
    }
    __syncthreads();
}

// ---------------------------------------------------------------------------
// QKV projection: OUT[M][768] = X[M][256] @ W[256][768] + bias
// ---------------------------------------------------------------------------
__global__ __launch_bounds__(256) void qkv_kernel(
        const float* __restrict__ X, const float* __restrict__ W,
        const float* __restrict__ bias, float* __restrict__ OUT) {
    const int R = 8;
    __shared__ float xs[R][CDIM];
    const int base = blockIdx.x * R;
    const int tid = threadIdx.x;
    #pragma unroll
    for (int r = 0; r < R; ++r) xs[r][tid] = X[(size_t)(base + r) * CDIM + tid];
    __syncthreads();
    for (int g = 0; g < 3; ++g) {
        const int j = g * 256 + tid;
        float acc[R];
        #pragma unroll
        for (int r = 0; r < R; ++r) acc[r] = 0.0f;
        const float* wp = W + j;
        for (int k = 0; k < CDIM; k += 4) {
            float w0 = wp[(size_t)(k+0)*768];
            float w1 = wp[(size_t)(k+1)*768];
            float w2 = wp[(size_t)(k+2)*768];
            float w3 = wp[(size_t)(k+3)*768];
            #pragma unroll
            for (int r = 0; r < R; ++r) {
                float4 xv = *reinterpret_cast<const float4*>(&xs[r][k]);
                acc[r] = fmaf(xv.x, w0, acc[r]);
                acc[r] = fmaf(xv.y, w1, acc[r]);
                acc[r] = fmaf(xv.z, w2, acc[r]);
                acc[r] = fmaf(xv.w, w3, acc[r]);
            }
        }
        const float bb = bias[j];
        #pragma unroll
        for (int r = 0; r < R; ++r) OUT[(size_t)(base + r) * 768 + j] = acc[r] + bb;
    }
}

// ---------------------------------------------------------------------------
// Per-(b,h) attention with online softmax. One WG per (b,h); thread = query row.
// ---------------------------------------------------------------------------
__global__ __launch_bounds__(256) void attn_kernel(
        const float* __restrict__ QKV, float* __restrict__ PO) {
    __shared__ float ks[NTOK][HD];
    __shared__ float vs[NTOK][HD];
    const int bh = blockIdx.x;
    const int b = bh >> 3;
    const int h = bh & 7;
    const int tid = threadIdx.x;
    for (int idx = tid; idx < NTOK * HD; idx += 256) {
        const int j = idx >> 5;
        const int d = idx & 31;
        const float* row = QKV + (size_t)(b * NTOK + j) * 768 + h * HD + d;
        ks[j][d] = row[256];
        vs[j][d] = row[512];
    }
    __syncthreads();
    float q[HD];
    const float* qrow = QKV + (size_t)(b * NTOK + tid) * 768 + h * HD;
    #pragma unroll
    for (int d = 0; d < HD; ++d) q[d] = qrow[d];
    const float scale = 0.17677669529663687f;   // 1/sqrt(32)
    float m = -1e30f, l = 0.0f;
    float po[HD];
    #pragma unroll
    for (int d = 0; d < HD; ++d) po[d] = 0.0f;
    for (int j = 0; j < NTOK; ++j) {
        float s = 0.0f;
        #pragma unroll
        for (int d = 0; d < HD; ++d) s = fmaf(q[d], ks[j][d], s);
        s *= scale;
        const float nm = fmaxf(m, s);
        const float corr = __expf(m - nm);
        const float p = __expf(s - nm);
        l = l * corr + p;
        #pragma unroll
        for (int d = 0; d < HD; ++d) po[d] = fmaf(po[d], corr, p * vs[j][d]);
        m = nm;
    }
    const float inv = 1.0f / l;
    float* dst = PO + (size_t)(b * NTOK + tid) * CDIM + h * HD;
    #pragma unroll
    for (int d = 0; d < HD; ++d) dst[d] = po[d] * inv;
}

// ---------------------------------------------------------------------------
// Out-proj + bias + residual(x) + LayerNorm(g1,b1) -> X1
// ---------------------------------------------------------------------------
__global__ __launch_bounds__(256) void oproj_ln_kernel(
        const float* __restrict__ PO, const float* __restrict__ WO,
        const float* __restrict__ BO, const float* __restrict__ X,
        const float* __restrict__ G1, const float* __restrict__ B1,
        float* __restrict__ X1) {
    const int R = 8;
    __shared__ float ps[R][CDIM];
    __shared__ float part_s[4][R], part_q[4][R];
    __shared__ float mb[R], rb[R];
    const int base = blockIdx.x * R;
    const int tid = threadIdx.x;
    #pragma unroll
    for (int r = 0; r < R; ++r) ps[r][tid] = PO[(size_t)(base + r) * CDIM + tid];
    __syncthreads();
    float acc[R];
    #pragma unroll
    for (int r = 0; r < R; ++r) acc[r] = 0.0f;
    const float* wp = WO + tid;
    for (int k = 0; k < CDIM; k += 4) {
        float w0 = wp[(size_t)(k+0)*CDIM];
        float w1 = wp[(size_t)(k+1)*CDIM];
        float w2 = wp[(size_t)(k+2)*CDIM];
        float w3 = wp[(size_t)(k+3)*CDIM];
        #pragma unroll
        for (int r = 0; r < R; ++r) {
            float4 xv = *reinterpret_cast<const float4*>(&ps[r][k]);
            acc[r] = fmaf(xv.x, w0, acc[r]);
            acc[r] = fmaf(xv.y, w1, acc[r]);
            acc[r] = fmaf(xv.z, w2, acc[r]);
            acc[r] = fmaf(xv.w, w3, acc[r]);
        }
    }
    const float bo = BO[tid];
    float val[R];
    #pragma unroll
    for (int r = 0; r < R; ++r)
        val[r] = acc[r] + bo + X[(size_t)(base + r) * CDIM + tid];
    ln_stats<R>(val, tid, part_s, part_q, mb, rb);
    const float g = G1[tid], bb = B1[tid];
    #pragma unroll
    for (int r = 0; r < R; ++r)
        X1[(size_t)(base + r) * CDIM + tid] = (val[r] - mb[r]) * rb[r] * g + bb;
}

// ---------------------------------------------------------------------------
// bf16 helpers
// ---------------------------------------------------------------------------
__device__ __forceinline__ unsigned int bf16_rne(float x) {
    unsigned int u = __float_as_uint(x);
    return (u + 0x7FFFu + ((u >> 16) & 1u)) >> 16;
}

// pack 8 consecutive k-weights (rows k=8g..8g+7 of col c, row stride CDIM)
__device__ __forceinline__ uint4 pack8(const float* p) {
    uint4 v;
    v.x = bf16_rne(p[0*CDIM]) | (bf16_rne(p[1*CDIM]) << 16);
    v.y = bf16_rne(p[2*CDIM]) | (bf16_rne(p[3*CDIM]) << 16);
    v.z = bf16_rne(p[4*CDIM]) | (bf16_rne(p[5*CDIM]) << 16);
    v.w = bf16_rne(p[6*CDIM]) | (bf16_rne(p[7*CDIM]) << 16);
    return v;
}

// acc[0..7] += buf[r][kbase..kbase+7] * w[0..7]   (8 bf16 weights in pv)
__device__ __forceinline__ void fma_chunk(
        const float (*buf)[CDIM], int kbase, uint4 pv, float* acc) {
    const float w0 = __uint_as_float(pv.x << 16);
    const float w1 = __uint_as_float(pv.x & 0xFFFF0000u);
    const float w2 = __uint_as_float(pv.y << 16);
    const float w3 = __uint_as_float(pv.y & 0xFFFF0000u);
    const float w4 = __uint_as_float(pv.z << 16);
    const float w5 = __uint_as_float(pv.z & 0xFFFF0000u);
    const float w6 = __uint_as_float(pv.w << 16);
    const float w7 = __uint_as_float(pv.w & 0xFFFF0000u);
    #pragma unroll
    for (int r = 0; r < 8; ++r) {
        const float4 x0 = *reinterpret_cast<const float4*>(&buf[r][kbase]);
        const float4 x1 = *reinterpret_cast<const float4*>(&buf[r][kbase + 4]);
        acc[r] = fmaf(x0.x, w0, acc[r]);
        acc[r] = fmaf(x0.y, w1, acc[r]);
        acc[r] = fmaf(x0.z, w2, acc[r]);
        acc[r] = fmaf(x0.w, w3, acc[r]);
        acc[r] = fmaf(x1.x, w4, acc[r]);
        acc[r] = fmaf(x1.y, w5, acc[r]);
        acc[r] = fmaf(x1.z, w6, acc[r]);
        acc[r] = fmaf(x1.w, w7, acc[r]);
    }
}

// ---------------------------------------------------------------------------
// One-time pack of WL2 -> [g][c] uint4 bf16 in workspace (L2-resident stream
// source for the ODE GEMV2).
// ---------------------------------------------------------------------------
__global__ __launch_bounds__(256) void packw2_kernel(
        const float* __restrict__ WL2, uint4* __restrict__ W2P) {
    const int g = blockIdx.x;       // 0..31
    const int c = threadIdx.x;      // 0..255
    W2P[(g << 8) + c] = pack8(WL2 + (size_t)(8 * g) * CDIM + c);
}

// ---------------------------------------------------------------------------
// Persistent ODE kernel — 256 threads (4 waves), 1 WG/CU (144KB dynamic LDS).
// Thread t owns column t for 8 rows.  Full-k GEMV per thread (no partials).
//   W1: bf16 in LDS, [kgroup][col] -> wave reads CONTIGUOUS uint4 (0 bank
//       conflicts; round 9's [col][k] layout was ~8-way conflicted).
//   W2: bf16 in global ws, [kgroup][col] -> 32 coalesced uint4 loads per
//       feval per thread, identical across WGs => L2-resident (512KB), and
//       at 128:1 FMA:load the latency hides under the unrolled FMA stream.
//   256-thread blocks escape the 64-VGPR cap that pinned every 1024-thread
//   variant (rounds 3-9); live set ~90 VGPRs, nothing to spill.
// ---------------------------------------------------------------------------
__global__ __launch_bounds__(256) void ode_kernel(
        const float* __restrict__ X1,
        const float* __restrict__ WL1, const float* __restrict__ BL1,
        const uint4* __restrict__ W2P, const float* __restrict__ BL2,
        const float* __restrict__ GN, const float* __restrict__ BN,
        const float* __restrict__ G2, const float* __restrict__ B2,
        const int* __restrict__ LT, const int* __restrict__ NSTEP,
        float* __restrict__ OUT) {
    extern __shared__ char smem[];
    uint4* W1p          = reinterpret_cast<uint4*>(smem);
    float (*bufA)[CDIM] = reinterpret_cast<float (*)[CDIM]>(smem + 131072);
    float (*bufB)[CDIM] = reinterpret_cast<float (*)[CDIM]>(smem + 139264);
    float (*pS)[8]      = reinterpret_cast<float (*)[8]>(smem + 147456);
    float (*pQ)[8]      = reinterpret_cast<float (*)[8]>(smem + 147584);
    float* mb           = reinterpret_cast<float*>(smem + 147712);
    float* rb           = reinterpret_cast<float*>(smem + 147744);

    const int t    = threadIdx.x;       // column
    const int lane = t & 63;
    const int wid  = t >> 6;
    const int wg = blockIdx.x;
    const int b  = wg >> 5;
    const int rg = wg & 31;
    const int base = b * NTOK + rg * 8;
    int steps = LT[b];
    const int ns = NSTEP[0];
    if (steps > ns) steps = ns;

    // ---- one-time: stage W1 into LDS as packed bf16, [g][c] layout.
    // Global reads coalesced (contiguous across t at each k); LDS writes
    // contiguous 16B per lane -> conflict-free.
    for (int g = 0; g < 32; ++g) {
        W1p[(g << 8) + t] = pack8(WL1 + (size_t)(8 * g) * CDIM + t);
    }
    __syncthreads();

    const float bl1 = BL1[t], bl2 = BL2[t];
    const float gnv = GN[t],  bnv = BN[t];
    const float g2v = G2[t],  b2v = B2[t];

    float y[8], x1v[8];
    #pragma unroll
    for (int r = 0; r < 8; ++r) {
        x1v[r] = X1[(size_t)(base + r) * CDIM + t];
        y[r] = x1v[r];
    }

    float kA[8], kB[8], kC[8], arg[8];
    #pragma unroll
    for (int r = 0; r < 8; ++r) arg[r] = y[r];

    for (int s = 0; s < steps; ++s) {
        for (int stage = 0; stage < 4; ++stage) {
            // ================= feval: arg -> kk =================
            #pragma unroll
            for (int r = 0; r < 8; ++r) bufA[r][t] = arg[r];
            __syncthreads();

            float acc[8];
            #pragma unroll
            for (int r = 0; r < 8; ++r) acc[r] = 0.0f;
            #pragma unroll 4
            for (int g = 0; g < 32; ++g) {
                const uint4 pv = W1p[(g << 8) + t];       // LDS, contiguous
                fma_chunk(bufA, g * 8, pv, acc);
            }
            #pragma unroll
            for (int r = 0; r < 8; ++r)
                bufB[r][t] = fmaxf(acc[r] + bl1, 0.0f);
            __syncthreads();

            #pragma unroll
            for (int r = 0; r < 8; ++r) acc[r] = 0.0f;
            #pragma unroll 4
            for (int g = 0; g < 32; ++g) {
                const uint4 pv = W2P[(g << 8) + t];       // global, L2-hit
                fma_chunk(bufB, g * 8, pv, acc);
            }
            float v[8];
            #pragma unroll
            for (int r = 0; r < 8; ++r) v[r] = acc[r] + bl2 + arg[r];

            // LayerNorm stats across 256 cols for the 8 rows
            #pragma unroll
            for (int r = 0; r < 8; ++r) {
                float sv = v[r];
                float qv = v[r] * v[r];
                #pragma unroll
                for (int off = 32; off > 0; off >>= 1) {
                    sv += __shfl_down(sv, off, 64);
                    qv += __shfl_down(qv, off, 64);
                }
                if (lane == 0) { pS[wid][r] = sv; pQ[wid][r] = qv; }
            }
            __syncthreads();
            if (t < 8) {
                const float S = pS[0][t] + pS[1][t] + pS[2][t] + pS[3][t];
                const float Q = pQ[0][t] + pQ[1][t] + pQ[2][t] + pQ[3][t];
                const float mean = S * (1.0f / CDIM);
                mb[t] = mean;
                rb[t] = rsqrtf(Q * (1.0f / CDIM) - mean * mean + LN_EPS);
            }
            __syncthreads();
            float kk[8];
            #pragma unroll
            for (int r = 0; r < 8; ++r)
                kk[r] = (v[r] - mb[r]) * rb[r] * gnv + bnv;
            // ================= RK4 (3/8 rule) combine =================
            if (stage == 0) {
                #pragma unroll
                for (int r = 0; r < 8; ++r) {
                    kA[r] = kk[r];
                    arg[r] = fmaf(DT_STEP * (1.0f/3.0f), kk[r], y[r]);
                }
            } else if (stage == 1) {
                #pragma unroll
                for (int r = 0; r < 8; ++r) {
                    kB[r] = kk[r];
                    arg[r] = fmaf(DT_STEP, kk[r] - kA[r] * (1.0f/3.0f), y[r]);
                }
            } else if (stage == 2) {
                #pragma unroll
                for (int r = 0; r < 8; ++r) {
                    kC[r] = kk[r];
                    arg[r] = fmaf(DT_STEP, kA[r] - kB[r] + kk[r], y[r]);
                }
            } else {
                #pragma unroll
                for (int r = 0; r < 8; ++r) {
                    y[r] = fmaf(DT_STEP * 0.125f,
                                kA[r] + 3.0f * (kB[r] + kC[r]) + kk[r], y[r]);
                    arg[r] = y[r];
                }
            }
        }
    }

    // ---- final: OUT = LN(x1 + y, g2, b2)
    float v[8];
    #pragma unroll
    for (int r = 0; r < 8; ++r) v[r] = x1v[r] + y[r];
    #pragma unroll
    for (int r = 0; r < 8; ++r) {
        float sv = v[r];
        float qv = v[r] * v[r];
        #pragma unroll
        for (int off = 32; off > 0; off >>= 1) {
            sv += __shfl_down(sv, off, 64);
            qv += __shfl_down(qv, off, 64);
        }
        if (lane == 0) { pS[wid][r] = sv; pQ[wid][r] = qv; }
    }
    __syncthreads();
    if (t < 8) {
        const float S = pS[0][t] + pS[1][t] + pS[2][t] + pS[3][t];
        const float Q = pQ[0][t] + pQ[1][t] + pQ[2][t] + pQ[3][t];
        const float mean = S * (1.0f / CDIM);
        mb[t] = mean;
        rb[t] = rsqrtf(Q * (1.0f / CDIM) - mean * mean + LN_EPS);
    }
    __syncthreads();
    #pragma unroll
    for (int r = 0; r < 8; ++r)
        OUT[(size_t)(base + r) * CDIM + t] = (v[r] - mb[r]) * rb[r] * g2v + b2v;
}

// ---------------------------------------------------------------------------
extern "C" void kernel_launch(void* const* d_in, const int* in_sizes, int n_in,
                              void* d_out, int out_size, void* d_ws, size_t ws_size,
                              hipStream_t stream) {
    const float* x    = (const float*)d_in[0];
    const float* wqkv = (const float*)d_in[1];
    const float* bqkv = (const float*)d_in[2];
    const float* wo   = (const float*)d_in[3];
    const float* bo   = (const float*)d_in[4];
    const float* g1   = (const float*)d_in[5];
    const float* b1   = (const float*)d_in[6];
    const float* g2   = (const float*)d_in[7];
    const float* b2   = (const float*)d_in[8];
    const float* wl1  = (const float*)d_in[9];
    const float* bl1  = (const float*)d_in[10];
    const float* wl2  = (const float*)d_in[11];
    const float* bl2  = (const float*)d_in[12];
    const float* gn   = (const float*)d_in[13];
    const float* bn   = (const float*)d_in[14];
    const int*   lt   = (const int*)d_in[15];
    const int*   nst  = (const int*)d_in[16];

    float* ws  = (float*)d_ws;
    float* qkv = ws;                              // M*768 f32
    float* po  = qkv + (size_t)MROWS * 768;       // M*256 f32
    float* x1  = po  + (size_t)MROWS * CDIM;      // M*256 f32
    uint4* w2p = (uint4*)(x1 + (size_t)MROWS * CDIM);  // 32*256 uint4 (128 KB)
    float* out = (float*)d_out;

    // Opt in to >64 KiB dynamic LDS (host-side, graph-capture safe, idempotent).
    (void)hipFuncSetAttribute(reinterpret_cast<const void*>(ode_kernel),
                              hipFuncAttributeMaxDynamicSharedMemorySize,
                              ODE_LDS_BYTES);

    hipLaunchKernelGGL(qkv_kernel, dim3(MROWS / 8), dim3(256), 0, stream,
                       x, wqkv, bqkv, qkv);
    hipLaunchKernelGGL(packw2_kernel, dim3(32), dim3(256), 0, stream,
                       wl2, w2p);
    hipLaunchKernelGGL(attn_kernel, dim3(BSZ * NHEAD), dim3(256), 0, stream,
                       qkv, po);
    hipLaunchKernelGGL(oproj_ln_kernel, dim3(MROWS / 8), dim3(256), 0, stream,
                       po, wo, bo, x, g1, b1, x1);
    hipLaunchKernelGGL(ode_kernel, dim3(MROWS / 8), dim3(256), ODE_LDS_BYTES, stream,
                       x1, wl1, bl1, w2p, bl2, gn, bn, g2, b2, lt, nst, out);
}